// Round 7
// baseline (368.761 us; speedup 1.0000x reference)
//
#include <hip/hip_runtime.h>
#include <hip/hip_fp16.h>

typedef _Float16 half8   __attribute__((ext_vector_type(8)));
typedef _Float16 half4_t __attribute__((ext_vector_type(4)));
typedef float    f32x4   __attribute__((ext_vector_type(4)));

#define HDIM  1024
#define BATCH 32
#define TLEN  1024
#define M_TOT (BATCH * TLEN)

#define BM 128
#define BN 128
#define BKF 64   // K-tile (halves); A row = 128 B
#define LDA 40   // fallback-path padded LDS stride (halves)

// ---------------- merged prep:
//   blocks 0..1023     : We = W[:,H:] -> fp16 (g-major, k-contiguous)
//   blocks 1024..2047  : qproj  q[b][g] = bias[g] + sum_h hidden[b][h]*W[g][h]
//   blocks 2048..18431 : enc fp32 -> fp16 streaming convert (fast path only)
__global__ void prep_k(const float* __restrict__ W, const float* __restrict__ hidden,
                       const float* __restrict__ bias, const float* __restrict__ enc,
                       _Float16* __restrict__ We16, float* __restrict__ q,
                       _Float16* __restrict__ enc16) {
    const int bid = blockIdx.x;
    const int t = threadIdx.x;
    if (bid < 1024) {
        int idx = bid * 256 + t;
        int g  = idx >> 8;
        int k4 = idx & 255;
        float4 f = *reinterpret_cast<const float4*>(W + (size_t)g * 2048 + 1024 + k4 * 4);
        half4_t h;
        h[0] = (_Float16)f.x; h[1] = (_Float16)f.y; h[2] = (_Float16)f.z; h[3] = (_Float16)f.w;
        *reinterpret_cast<half4_t*>(We16 + (size_t)idx * 4) = h;
    } else if (bid < 2048) {
        int g = bid - 1024;
        int wave = t >> 6, lane = t & 63;
        float acc[BATCH];
#pragma unroll
        for (int b = 0; b < BATCH; b++) acc[b] = 0.f;
        const float* wr = W + (size_t)g * 2048;
        for (int h = t; h < HDIM; h += 256) {
            float w = wr[h];
#pragma unroll
            for (int b = 0; b < BATCH; b++) acc[b] = fmaf(w, hidden[b * HDIM + h], acc[b]);
        }
        __shared__ float sm[4 * BATCH];
#pragma unroll
        for (int b = 0; b < BATCH; b++) {
            float s = acc[b];
#pragma unroll
            for (int off = 32; off >= 1; off >>= 1) s += __shfl_xor(s, off);
            if (lane == 0) sm[wave * BATCH + b] = s;
        }
        __syncthreads();
        if (t < BATCH) {
            float s = sm[t] + sm[BATCH + t] + sm[2 * BATCH + t] + sm[3 * BATCH + t];
            q[t * HDIM + g] = s + bias[g];
        }
    } else {
        size_t i = ((size_t)(bid - 2048) * 256 + t) * 8;
        float4 f0 = *reinterpret_cast<const float4*>(enc + i);
        float4 f1 = *reinterpret_cast<const float4*>(enc + i + 4);
        half8 h;
        h[0] = (_Float16)f0.x; h[1] = (_Float16)f0.y; h[2] = (_Float16)f0.z; h[3] = (_Float16)f0.w;
        h[4] = (_Float16)f1.x; h[5] = (_Float16)f1.y; h[6] = (_Float16)f1.z; h[7] = (_Float16)f1.w;
        *reinterpret_cast<half8*>(enc16 + i) = h;
    }
}

__device__ __forceinline__ void async16(const void* g, void* l) {
    __builtin_amdgcn_global_load_lds(
        (const __attribute__((address_space(1))) void*)g,
        (__attribute__((address_space(3))) void*)l, 16, 0, 0);
}

// ---------------- FAST: r0 128x128 structure, B read DIRECTLY from global (L2-resident
// 2 MB We16 — no LDS staging for B), A double-buffered in LDS -> ONE barrier per K-tile.
// Per tile: 8 global_load_dwordx4 (bf, issued FIRST so MFMA's bf-wait leaves A-staging
// asyncs in flight) + 4 async16 (A next tile, other buffer) + 8 ds_read_b128 (af) +
// 32 MFMA + __syncthreads (drains vmcnt; orders buffer swap).
// Dbuf audit: iteration t reads As[p=t&1], stages t+1 into As[p^1]; regions disjoint;
// barrier at iteration end = all waves done reading p AND staging drained, so t+1 reads
// p^1 (complete) and overwrites p (no live readers). A swizzle/read addressing identical
// to the r0-verified kernel; B global address = unswizzled source of the r0 B formula.
__global__ __launch_bounds__(256)
void attn_gemm_bg_k(const _Float16* __restrict__ enc16,
                    const _Float16* __restrict__ We16,
                    const float* __restrict__ q, const float* __restrict__ v,
                    float* __restrict__ energ) {
    __shared__ _Float16 As[2 * BM * BKF];   // 2 x 16 KB, XOR chunk-swizzled rows

    const int tid  = threadIdx.x;
    const int id   = blockIdx.x;
    const int xcd  = id & 7;
    const int w    = id >> 3;
    const int m0   = (xcd * 32 + (w >> 3)) * BM;
    const int n0   = (w & 7) * BN;
    const int nblk = w & 7;
    const int wave = tid >> 6;
    const int lane = tid & 63;
    const int quad = lane >> 4;
    const int l16  = lane & 15;
    const int wm   = (wave & 1) * 64;
    const int wn   = (wave >> 1) * 64;

    f32x4 acc[4][4];
#pragma unroll
    for (int i = 0; i < 4; i++)
#pragma unroll
        for (int j = 0; j < 4; j++) acc[i][j] = {0.f, 0.f, 0.f, 0.f};

    // A staging (r0 pattern): issue ii covers rows wave*32+ii*8+(lane>>3);
    // fetched global chunk c = (lane&7)^(lane>>3) -> linear LDS slot lane&7.
    const int srow = wave * 32 + (lane >> 3);
    const int scol = ((lane & 7) ^ (lane >> 3)) * 8;          // halves
    const _Float16* gA = enc16 + (size_t)(m0 + srow) * HDIM + scol;
    const int lA = wave * 2048 + (lane & 63) * 8 - (lane & 7) * 8 + (lane & 7) * 8; // = wave*2048 + lane*8
    const size_t istep = (size_t)8 * HDIM;

    // A frag read offsets (r0 verified): row ra wants chunk c=s*4+quad at slot c^(ra&7)
    int aoff[2][4];
#pragma unroll
    for (int s = 0; s < 2; s++)
#pragma unroll
        for (int i = 0; i < 4; i++) {
            int ra = wm + i * 16 + l16;
            aoff[s][i] = ra * BKF + (((s * 4 + quad) ^ (l16 & 7)) * 8);
        }

    // B per-lane global base: frag (s,i) at k0 lives at
    // We16[(n0 + wn + i*16 + l16)*HDIM + k0 + (s*4+quad)*8]
    const _Float16* gBf = We16 + (size_t)(n0 + wn + l16) * HDIM + quad * 8;

    // prologue: stage tile 0 -> buf 0
#pragma unroll
    for (int ii = 0; ii < 4; ii++)
        async16(gA + ii * istep, &As[wave * 2048 + ii * 512 + lane * 8]);
    __syncthreads();

    for (int t = 0; t < 16; t++) {
        const int k0 = t * BKF;
        const int pb = (t & 1) * (BM * BKF);

        // B frags: global loads FIRST (oldest in vmcnt queue)
        half8 bf[2][4];
#pragma unroll
        for (int s = 0; s < 2; s++)
#pragma unroll
            for (int i = 0; i < 4; i++)
                bf[s][i] = *reinterpret_cast<const half8*>(
                    gBf + (size_t)(i * 16) * HDIM + s * 32 + k0);

        // stage next A tile into the other buffer (no barrier needed: disjoint region)
        if (t < 15) {
            const int qb = ((t + 1) & 1) * (BM * BKF);
            const int kn = k0 + BKF;
#pragma unroll
            for (int ii = 0; ii < 4; ii++)
                async16(gA + kn + ii * istep, &As[qb + wave * 2048 + ii * 512 + lane * 8]);
        }

        // A frags from LDS buffer p
        half8 af[2][4];
#pragma unroll
        for (int s = 0; s < 2; s++)
#pragma unroll
            for (int i = 0; i < 4; i++)
                af[s][i] = *reinterpret_cast<const half8*>(&As[pb + aoff[s][i]]);

#pragma unroll
        for (int s = 0; s < 2; s++)
#pragma unroll
            for (int mi = 0; mi < 4; mi++)
#pragma unroll
                for (int ni = 0; ni < 4; ni++)
                    acc[mi][ni] = __builtin_amdgcn_mfma_f32_16x16x32_f16(af[s][mi], bf[s][ni], acc[mi][ni], 0, 0, 0);

        __syncthreads();   // drains vmcnt/lgkmcnt; orders buffer swap
    }

    // epilogue (r5 verified): C/D col = l16, row = quad*4 + r; 16 partials/row,
    // slot = (m0+row)*16 + nblk*2 + (wn>>6) — exactly one writer per slot.
    const int bidx = m0 >> 10;
    const int half = wn >> 6;
    float qv[4], vv[4];
#pragma unroll
    for (int ni = 0; ni < 4; ni++) {
        int g = n0 + wn + ni * 16 + l16;
        qv[ni] = q[bidx * HDIM + g];
        vv[ni] = v[g];
    }
#pragma unroll
    for (int mi = 0; mi < 4; mi++) {
#pragma unroll
        for (int r = 0; r < 4; r++) {
            int row = wm + mi * 16 + quad * 4 + r;
            float s = 0.f;
#pragma unroll
            for (int ni = 0; ni < 4; ni++) {
                float pre = acc[mi][ni][r] + qv[ni];
                float e = __expf(2.f * pre);
                float th = 1.f - 2.f / (e + 1.f);
                s = fmaf(th, vv[ni], s);
            }
            s += __shfl_xor(s, 1);
            s += __shfl_xor(s, 2);
            s += __shfl_xor(s, 4);
            s += __shfl_xor(s, 8);
            if (l16 == 0) energ[(size_t)(m0 + row) * 16 + nblk * 2 + half] = s;
        }
    }
}

// ---------------- FALLBACK: fp32 A on-the-fly convert (BK=32, padded LDS) ----------------
__global__ __launch_bounds__(256, 2)
void attn_gemm_k(const float* __restrict__ enc, const _Float16* __restrict__ We16,
                 const float* __restrict__ q, const float* __restrict__ v,
                 float* __restrict__ energ) {
    __shared__ _Float16 As[BM * LDA];
    __shared__ _Float16 Bs[BN * LDA];

    const int tid  = threadIdx.x;
    const int m0   = blockIdx.x * BM;
    const int n0   = blockIdx.y * BN;
    const int wave = tid >> 6;
    const int lane = tid & 63;
    const int quad = lane >> 4;
    const int l16  = lane & 15;
    const int wm   = (wave & 1) * 64;
    const int wn   = (wave >> 1) * 64;

    const int srow = tid >> 1;
    const int scol = (tid & 1) * 16;

    f32x4 acc[4][4];
#pragma unroll
    for (int i = 0; i < 4; i++)
#pragma unroll
        for (int j = 0; j < 4; j++) acc[i][j] = {0.f, 0.f, 0.f, 0.f};

    const float*    ag = enc  + (size_t)(m0 + srow) * HDIM + scol;
    const _Float16* bg = We16 + (size_t)(n0 + srow) * HDIM + scol;
    _Float16* aw = &As[srow * LDA + scol];
    _Float16* bw = &Bs[srow * LDA + scol];

    for (int k0 = 0; k0 < HDIM; k0 += 32) {
        float4 a0 = *reinterpret_cast<const float4*>(ag + k0 + 0);
        float4 a1 = *reinterpret_cast<const float4*>(ag + k0 + 4);
        float4 a2 = *reinterpret_cast<const float4*>(ag + k0 + 8);
        float4 a3 = *reinterpret_cast<const float4*>(ag + k0 + 12);
        float4 b0 = *reinterpret_cast<const float4*>(bg + k0);
        float4 b1 = *reinterpret_cast<const float4*>(bg + k0 + 8);

        __syncthreads();

        half8 ha0, ha1;
        ha0[0] = (_Float16)a0.x; ha0[1] = (_Float16)a0.y; ha0[2] = (_Float16)a0.z; ha0[3] = (_Float16)a0.w;
        ha0[4] = (_Float16)a1.x; ha0[5] = (_Float16)a1.y; ha0[6] = (_Float16)a1.z; ha0[7] = (_Float16)a1.w;
        ha1[0] = (_Float16)a2.x; ha1[1] = (_Float16)a2.y; ha1[2] = (_Float16)a2.z; ha1[3] = (_Float16)a2.w;
        ha1[4] = (_Float16)a3.x; ha1[5] = (_Float16)a3.y; ha1[6] = (_Float16)a3.z; ha1[7] = (_Float16)a3.w;
        *reinterpret_cast<half8*>(aw)     = ha0;
        *reinterpret_cast<half8*>(aw + 8) = ha1;
        *reinterpret_cast<float4*>(bw)     = b0;
        *reinterpret_cast<float4*>(bw + 8) = b1;

        __syncthreads();

        half8 af[4], bf[4];
#pragma unroll
        for (int i = 0; i < 4; i++) {
            af[i] = *reinterpret_cast<const half8*>(&As[(wm + i * 16 + l16) * LDA + quad * 8]);
            bf[i] = *reinterpret_cast<const half8*>(&Bs[(wn + i * 16 + l16) * LDA + quad * 8]);
        }
#pragma unroll
        for (int mi = 0; mi < 4; mi++)
#pragma unroll
            for (int ni = 0; ni < 4; ni++)
                acc[mi][ni] = __builtin_amdgcn_mfma_f32_16x16x32_f16(af[mi], bf[ni], acc[mi][ni], 0, 0, 0);
    }

    const int bidx = m0 >> 10;
    const int half = wn >> 6;
    float qv[4], vv[4];
#pragma unroll
    for (int ni = 0; ni < 4; ni++) {
        int g = n0 + wn + ni * 16 + l16;
        qv[ni] = q[bidx * HDIM + g];
        vv[ni] = v[g];
    }
#pragma unroll
    for (int mi = 0; mi < 4; mi++) {
#pragma unroll
        for (int r = 0; r < 4; r++) {
            int row = wm + mi * 16 + quad * 4 + r;
            float s = 0.f;
#pragma unroll
            for (int ni = 0; ni < 4; ni++) {
                float pre = acc[mi][ni][r] + qv[ni];
                float e = __expf(2.f * pre);
                float th = 1.f - 2.f / (e + 1.f);
                s = fmaf(th, vv[ni], s);
            }
            s += __shfl_xor(s, 1);
            s += __shfl_xor(s, 2);
            s += __shfl_xor(s, 4);
            s += __shfl_xor(s, 8);
            if (l16 == 0) energ[(size_t)(m0 + row) * 16 + blockIdx.y * 2 + half] = s;
        }
    }
}

// ---------------- softmax over t per batch row (sums the 16 partials) ----------
__global__ void softmax_k(const float* __restrict__ energ, float* __restrict__ out) {
    int b = blockIdx.x;
    int t = threadIdx.x;
    int wave = t >> 6, lane = t & 63;
    __shared__ float smax[4], ssum[4];
    float e[4];
#pragma unroll
    for (int i = 0; i < 4; i++) {
        size_t m = (size_t)b * TLEN + t + i * 256;
        const float* p = energ + m * 16;
        f32x4 p0 = *reinterpret_cast<const f32x4*>(p);
        f32x4 p1 = *reinterpret_cast<const f32x4*>(p + 4);
        f32x4 p2 = *reinterpret_cast<const f32x4*>(p + 8);
        f32x4 p3 = *reinterpret_cast<const f32x4*>(p + 12);
        e[i] = ((p0[0] + p0[1]) + (p0[2] + p0[3])) + ((p1[0] + p1[1]) + (p1[2] + p1[3]))
             + ((p2[0] + p2[1]) + (p2[2] + p2[3])) + ((p3[0] + p3[1]) + (p3[2] + p3[3]));
    }
    float m = fmaxf(fmaxf(e[0], e[1]), fmaxf(e[2], e[3]));
#pragma unroll
    for (int off = 32; off >= 1; off >>= 1) m = fmaxf(m, __shfl_xor(m, off));
    if (lane == 0) smax[wave] = m;
    __syncthreads();
    float M = fmaxf(fmaxf(smax[0], smax[1]), fmaxf(smax[2], smax[3]));
    float x[4]; float s = 0.f;
#pragma unroll
    for (int i = 0; i < 4; i++) { x[i] = __expf(e[i] - M); s += x[i]; }
#pragma unroll
    for (int off = 32; off >= 1; off >>= 1) s += __shfl_xor(s, off);
    if (lane == 0) ssum[wave] = s;
    __syncthreads();
    float S = ssum[0] + ssum[1] + ssum[2] + ssum[3];
    float inv = 1.f / S;
#pragma unroll
    for (int i = 0; i < 4; i++) out[b * TLEN + t + i * 256] = x[i] * inv;
}

extern "C" void kernel_launch(void* const* d_in, const int* in_sizes, int n_in,
                              void* d_out, int out_size, void* d_ws, size_t ws_size,
                              hipStream_t stream) {
    const float* hidden = (const float*)d_in[0];   // (1, 32, 1024) fp32
    const float* enc    = (const float*)d_in[1];   // (32, 1024, 1024) fp32
    const float* W      = (const float*)d_in[2];   // (1024, 2048) fp32
    const float* bias   = (const float*)d_in[3];   // (1024,) fp32
    const float* v      = (const float*)d_in[4];   // (1024,) fp32
    float* out = (float*)d_out;                    // (32, 1, 1024) fp32

    char* ws = (char*)d_ws;
    float*    q     = (float*)ws;                            // 128 KB
    float*    energ = (float*)(ws + 131072);                 // 2 MB (16 partials x M_TOT)
    _Float16* We16  = (_Float16*)(ws + 131072 + 2097152);    // 2 MB
    _Float16* enc16 = (_Float16*)(ws + 131072 + 2097152 + 2097152);  // 64 MB
    const size_t need_fast = 131072 + 2097152 + 2097152 + (size_t)M_TOT * HDIM * 2;  // ~68 MB

    if (ws_size >= need_fast) {
        prep_k<<<dim3(18432), 256, 0, stream>>>(W, hidden, bias, enc, We16, q, enc16);
        attn_gemm_bg_k<<<dim3(2048), 256, 0, stream>>>(enc16, We16, q, v, energ);
    } else {
        prep_k<<<dim3(2048), 256, 0, stream>>>(W, hidden, bias, enc, We16, q, enc16);
        attn_gemm_k<<<dim3(256, 8), 256, 0, stream>>>(enc, We16, q, v, energ);
    }
    softmax_k<<<dim3(BATCH), 256, 0, stream>>>(energ, out);
}

// Round 8
// 314.727 us; speedup vs baseline: 1.1717x; 1.1717x over previous
//
#include <hip/hip_runtime.h>
#include <hip/hip_fp16.h>

typedef _Float16 half8   __attribute__((ext_vector_type(8)));
typedef _Float16 half4_t __attribute__((ext_vector_type(4)));
typedef float    f32x4   __attribute__((ext_vector_type(4)));

#define HDIM  1024
#define BATCH 32
#define TLEN  1024
#define M_TOT (BATCH * TLEN)

#define BM 128
#define BN 128
#define BKF 64   // K-tile (halves); row = 128 B
#define LDA 40   // fallback-path padded LDS stride (halves)

// ---------------- merged prep:
//   blocks 0..1023     : We = W[:,H:] -> fp16 (g-major, k-contiguous)
//   blocks 1024..2047  : qproj  q[b][g] = bias[g] + sum_h hidden[b][h]*W[g][h]
//   blocks 2048..18431 : enc fp32 -> fp16 streaming convert (fast path only)
__global__ void prep_k(const float* __restrict__ W, const float* __restrict__ hidden,
                       const float* __restrict__ bias, const float* __restrict__ enc,
                       _Float16* __restrict__ We16, float* __restrict__ q,
                       _Float16* __restrict__ enc16) {
    const int bid = blockIdx.x;
    const int t = threadIdx.x;
    if (bid < 1024) {
        int idx = bid * 256 + t;
        int g  = idx >> 8;
        int k4 = idx & 255;
        float4 f = *reinterpret_cast<const float4*>(W + (size_t)g * 2048 + 1024 + k4 * 4);
        half4_t h;
        h[0] = (_Float16)f.x; h[1] = (_Float16)f.y; h[2] = (_Float16)f.z; h[3] = (_Float16)f.w;
        *reinterpret_cast<half4_t*>(We16 + (size_t)idx * 4) = h;
    } else if (bid < 2048) {
        int g = bid - 1024;
        int wave = t >> 6, lane = t & 63;
        float acc[BATCH];
#pragma unroll
        for (int b = 0; b < BATCH; b++) acc[b] = 0.f;
        const float* wr = W + (size_t)g * 2048;
        for (int h = t; h < HDIM; h += 256) {
            float w = wr[h];
#pragma unroll
            for (int b = 0; b < BATCH; b++) acc[b] = fmaf(w, hidden[b * HDIM + h], acc[b]);
        }
        __shared__ float sm[4 * BATCH];
#pragma unroll
        for (int b = 0; b < BATCH; b++) {
            float s = acc[b];
#pragma unroll
            for (int off = 32; off >= 1; off >>= 1) s += __shfl_xor(s, off);
            if (lane == 0) sm[wave * BATCH + b] = s;
        }
        __syncthreads();
        if (t < BATCH) {
            float s = sm[t] + sm[BATCH + t] + sm[2 * BATCH + t] + sm[3 * BATCH + t];
            q[t * HDIM + g] = s + bias[g];
        }
    } else {
        size_t i = ((size_t)(bid - 2048) * 256 + t) * 8;
        float4 f0 = *reinterpret_cast<const float4*>(enc + i);
        float4 f1 = *reinterpret_cast<const float4*>(enc + i + 4);
        half8 h;
        h[0] = (_Float16)f0.x; h[1] = (_Float16)f0.y; h[2] = (_Float16)f0.z; h[3] = (_Float16)f0.w;
        h[4] = (_Float16)f1.x; h[5] = (_Float16)f1.y; h[6] = (_Float16)f1.z; h[7] = (_Float16)f1.w;
        *reinterpret_cast<half8*>(enc16 + i) = h;
    }
}

__device__ __forceinline__ void async16(const void* g, void* l) {
    __builtin_amdgcn_global_load_lds(
        (const __attribute__((address_space(1))) void*)g,
        (__attribute__((address_space(3))) void*)l, 16, 0, 0);
}

// ---------------- FAST: r5 kernel + double-buffered A AND B -> ONE barrier per K-tile.
// LDS 64 KB -> 2 blocks/CU co-resident (cross-block overlap hides barrier skew, m114).
// Iteration t: issue staging of tile t+1 into buf p^1 (8 async16, FIRST so latency hides
// under the ds_reads+MFMA), read frags from buf p (16 ds_read_b128), 32 MFMA, one
// __syncthreads (compiler drains vmcnt+lgkmcnt).
// Dbuf audit: staging(t+1)->p^1 disjoint from reads(t)->p; barrier(t) orders staging
// completion before reads(t+1) AND all reads of p before staging(t+2) overwrites p.
// Addressing/swizzle/staging map/epilogue byte-identical to the r5/r6-verified kernel.
__global__ __launch_bounds__(256)
void attn_gemm_db_k(const _Float16* __restrict__ enc16,
                    const _Float16* __restrict__ We16,
                    const float* __restrict__ q, const float* __restrict__ v,
                    float* __restrict__ energ) {
    __shared__ _Float16 As[2 * BM * BKF];   // 2 x 16 KB, XOR chunk-swizzled rows
    __shared__ _Float16 Bs[2 * BN * BKF];   // 2 x 16 KB

    const int tid  = threadIdx.x;
    const int id   = blockIdx.x;
    const int xcd  = id & 7;
    const int w    = id >> 3;
    const int m0   = (xcd * 32 + (w >> 3)) * BM;
    const int n0   = (w & 7) * BN;
    const int nblk = w & 7;
    const int wave = tid >> 6;
    const int lane = tid & 63;
    const int quad = lane >> 4;
    const int l16  = lane & 15;
    const int wm   = (wave & 1) * 64;
    const int wn   = (wave >> 1) * 64;

    f32x4 acc[4][4];
#pragma unroll
    for (int i = 0; i < 4; i++)
#pragma unroll
        for (int j = 0; j < 4; j++) acc[i][j] = {0.f, 0.f, 0.f, 0.f};

    // staging (r0-verified): issue ii covers rows wave*32+ii*8+(lane>>3);
    // fetched global chunk c = (lane&7)^(lane>>3) -> linear LDS slot lane&7.
    const int srow = wave * 32 + (lane >> 3);
    const int scol = ((lane & 7) ^ (lane >> 3)) * 8;          // halves
    const _Float16* gA = enc16 + (size_t)(m0 + srow) * HDIM + scol;
    const _Float16* gB = We16  + (size_t)(n0 + srow) * HDIM + scol;
    _Float16* lA = As + wave * 2048;      // wave-uniform LDS base (HW adds lane*16B)
    _Float16* lB = Bs + wave * 2048;
    const size_t istep = (size_t)8 * HDIM;

    // frag read offsets (r0-verified): row r wants chunk c=s*4+quad, stored at c^(r&7)
    int aoff[2][4], boff[2][4];
#pragma unroll
    for (int s = 0; s < 2; s++)
#pragma unroll
        for (int i = 0; i < 4; i++) {
            int ra = wm + i * 16 + l16;
            int rb = wn + i * 16 + l16;
            aoff[s][i] = ra * BKF + (((s * 4 + quad) ^ (l16 & 7)) * 8);
            boff[s][i] = rb * BKF + (((s * 4 + quad) ^ (l16 & 7)) * 8);
        }

    // prologue: stage tile 0 -> buffer 0
#pragma unroll
    for (int ii = 0; ii < 4; ii++) {
        async16(gA + ii * istep, lA + ii * 512);
        async16(gB + ii * istep, lB + ii * 512);
    }
    __syncthreads();

    for (int t = 0; t < 16; t++) {
        const int pb = (t & 1) * (BM * BKF);          // 8192-half buffer offset

        // issue next-tile staging FIRST (into the other buffer; no barrier needed)
        if (t < 15) {
            const int qb = ((t + 1) & 1) * (BM * BKF);
            const int kn = (t + 1) * BKF;
#pragma unroll
            for (int ii = 0; ii < 4; ii++) {
                async16(gA + kn + ii * istep, lA + qb + ii * 512);
                async16(gB + kn + ii * istep, lB + qb + ii * 512);
            }
        }

        half8 af[2][4], bf[2][4];
#pragma unroll
        for (int s = 0; s < 2; s++)
#pragma unroll
            for (int i = 0; i < 4; i++) {
                af[s][i] = *reinterpret_cast<const half8*>(&As[pb + aoff[s][i]]);
                bf[s][i] = *reinterpret_cast<const half8*>(&Bs[pb + boff[s][i]]);
            }

#pragma unroll
        for (int s = 0; s < 2; s++)
#pragma unroll
            for (int mi = 0; mi < 4; mi++)
#pragma unroll
                for (int ni = 0; ni < 4; ni++)
                    acc[mi][ni] = __builtin_amdgcn_mfma_f32_16x16x32_f16(af[s][mi], bf[s][ni], acc[mi][ni], 0, 0, 0);

        __syncthreads();   // drains vmcnt+lgkmcnt; orders buffer swap
    }

    // epilogue (r5-verified): C/D col = l16, row = quad*4 + r; 16 partials/row,
    // slot = (m0+row)*16 + nblk*2 + (wn>>6) — exactly one writer per slot.
    const int bidx = m0 >> 10;
    const int half = wn >> 6;
    float qv[4], vv[4];
#pragma unroll
    for (int ni = 0; ni < 4; ni++) {
        int g = n0 + wn + ni * 16 + l16;
        qv[ni] = q[bidx * HDIM + g];
        vv[ni] = v[g];
    }
#pragma unroll
    for (int mi = 0; mi < 4; mi++) {
#pragma unroll
        for (int r = 0; r < 4; r++) {
            int row = wm + mi * 16 + quad * 4 + r;
            float s = 0.f;
#pragma unroll
            for (int ni = 0; ni < 4; ni++) {
                float pre = acc[mi][ni][r] + qv[ni];
                float e = __expf(2.f * pre);
                float th = 1.f - 2.f / (e + 1.f);
                s = fmaf(th, vv[ni], s);
            }
            s += __shfl_xor(s, 1);
            s += __shfl_xor(s, 2);
            s += __shfl_xor(s, 4);
            s += __shfl_xor(s, 8);
            if (l16 == 0) energ[(size_t)(m0 + row) * 16 + nblk * 2 + half] = s;
        }
    }
}

// ---------------- FALLBACK: fp32 A on-the-fly convert (BK=32, padded LDS) ----------------
__global__ __launch_bounds__(256, 2)
void attn_gemm_k(const float* __restrict__ enc, const _Float16* __restrict__ We16,
                 const float* __restrict__ q, const float* __restrict__ v,
                 float* __restrict__ energ) {
    __shared__ _Float16 As[BM * LDA];
    __shared__ _Float16 Bs[BN * LDA];

    const int tid  = threadIdx.x;
    const int m0   = blockIdx.x * BM;
    const int n0   = blockIdx.y * BN;
    const int wave = tid >> 6;
    const int lane = tid & 63;
    const int quad = lane >> 4;
    const int l16  = lane & 15;
    const int wm   = (wave & 1) * 64;
    const int wn   = (wave >> 1) * 64;

    const int srow = tid >> 1;
    const int scol = (tid & 1) * 16;

    f32x4 acc[4][4];
#pragma unroll
    for (int i = 0; i < 4; i++)
#pragma unroll
        for (int j = 0; j < 4; j++) acc[i][j] = {0.f, 0.f, 0.f, 0.f};

    const float*    ag = enc  + (size_t)(m0 + srow) * HDIM + scol;
    const _Float16* bg = We16 + (size_t)(n0 + srow) * HDIM + scol;
    _Float16* aw = &As[srow * LDA + scol];
    _Float16* bw = &Bs[srow * LDA + scol];

    for (int k0 = 0; k0 < HDIM; k0 += 32) {
        float4 a0 = *reinterpret_cast<const float4*>(ag + k0 + 0);
        float4 a1 = *reinterpret_cast<const float4*>(ag + k0 + 4);
        float4 a2 = *reinterpret_cast<const float4*>(ag + k0 + 8);
        float4 a3 = *reinterpret_cast<const float4*>(ag + k0 + 12);
        float4 b0 = *reinterpret_cast<const float4*>(bg + k0);
        float4 b1 = *reinterpret_cast<const float4*>(bg + k0 + 8);

        __syncthreads();

        half8 ha0, ha1;
        ha0[0] = (_Float16)a0.x; ha0[1] = (_Float16)a0.y; ha0[2] = (_Float16)a0.z; ha0[3] = (_Float16)a0.w;
        ha0[4] = (_Float16)a1.x; ha0[5] = (_Float16)a1.y; ha0[6] = (_Float16)a1.z; ha0[7] = (_Float16)a1.w;
        ha1[0] = (_Float16)a2.x; ha1[1] = (_Float16)a2.y; ha1[2] = (_Float16)a2.z; ha1[3] = (_Float16)a2.w;
        ha1[4] = (_Float16)a3.x; ha1[5] = (_Float16)a3.y; ha1[6] = (_Float16)a3.z; ha1[7] = (_Float16)a3.w;
        *reinterpret_cast<half8*>(aw)     = ha0;
        *reinterpret_cast<half8*>(aw + 8) = ha1;
        *reinterpret_cast<float4*>(bw)     = b0;
        *reinterpret_cast<float4*>(bw + 8) = b1;

        __syncthreads();

        half8 af[4], bf[4];
#pragma unroll
        for (int i = 0; i < 4; i++) {
            af[i] = *reinterpret_cast<const half8*>(&As[(wm + i * 16 + l16) * LDA + quad * 8]);
            bf[i] = *reinterpret_cast<const half8*>(&Bs[(wn + i * 16 + l16) * LDA + quad * 8]);
        }
#pragma unroll
        for (int mi = 0; mi < 4; mi++)
#pragma unroll
            for (int ni = 0; ni < 4; ni++)
                acc[mi][ni] = __builtin_amdgcn_mfma_f32_16x16x32_f16(af[mi], bf[ni], acc[mi][ni], 0, 0, 0);
    }

    const int bidx = m0 >> 10;
    const int half = wn >> 6;
    float qv[4], vv[4];
#pragma unroll
    for (int ni = 0; ni < 4; ni++) {
        int g = n0 + wn + ni * 16 + l16;
        qv[ni] = q[bidx * HDIM + g];
        vv[ni] = v[g];
    }
#pragma unroll
    for (int mi = 0; mi < 4; mi++) {
#pragma unroll
        for (int r = 0; r < 4; r++) {
            int row = wm + mi * 16 + quad * 4 + r;
            float s = 0.f;
#pragma unroll
            for (int ni = 0; ni < 4; ni++) {
                float pre = acc[mi][ni][r] + qv[ni];
                float e = __expf(2.f * pre);
                float th = 1.f - 2.f / (e + 1.f);
                s = fmaf(th, vv[ni], s);
            }
            s += __shfl_xor(s, 1);
            s += __shfl_xor(s, 2);
            s += __shfl_xor(s, 4);
            s += __shfl_xor(s, 8);
            if (l16 == 0) energ[(size_t)(m0 + row) * 16 + blockIdx.y * 2 + half] = s;
        }
    }
}

// ---------------- softmax over t per batch row (sums the 16 partials) ----------
__global__ void softmax_k(const float* __restrict__ energ, float* __restrict__ out) {
    int b = blockIdx.x;
    int t = threadIdx.x;
    int wave = t >> 6, lane = t & 63;
    __shared__ float smax[4], ssum[4];
    float e[4];
#pragma unroll
    for (int i = 0; i < 4; i++) {
        size_t m = (size_t)b * TLEN + t + i * 256;
        const float* p = energ + m * 16;
        f32x4 p0 = *reinterpret_cast<const f32x4*>(p);
        f32x4 p1 = *reinterpret_cast<const f32x4*>(p + 4);
        f32x4 p2 = *reinterpret_cast<const f32x4*>(p + 8);
        f32x4 p3 = *reinterpret_cast<const f32x4*>(p + 12);
        e[i] = ((p0[0] + p0[1]) + (p0[2] + p0[3])) + ((p1[0] + p1[1]) + (p1[2] + p1[3]))
             + ((p2[0] + p2[1]) + (p2[2] + p2[3])) + ((p3[0] + p3[1]) + (p3[2] + p3[3]));
    }
    float m = fmaxf(fmaxf(e[0], e[1]), fmaxf(e[2], e[3]));
#pragma unroll
    for (int off = 32; off >= 1; off >>= 1) m = fmaxf(m, __shfl_xor(m, off));
    if (lane == 0) smax[wave] = m;
    __syncthreads();
    float M = fmaxf(fmaxf(smax[0], smax[1]), fmaxf(smax[2], smax[3]));
    float x[4]; float s = 0.f;
#pragma unroll
    for (int i = 0; i < 4; i++) { x[i] = __expf(e[i] - M); s += x[i]; }
#pragma unroll
    for (int off = 32; off >= 1; off >>= 1) s += __shfl_xor(s, off);
    if (lane == 0) ssum[wave] = s;
    __syncthreads();
    float S = ssum[0] + ssum[1] + ssum[2] + ssum[3];
    float inv = 1.f / S;
#pragma unroll
    for (int i = 0; i < 4; i++) out[b * TLEN + t + i * 256] = x[i] * inv;
}

extern "C" void kernel_launch(void* const* d_in, const int* in_sizes, int n_in,
                              void* d_out, int out_size, void* d_ws, size_t ws_size,
                              hipStream_t stream) {
    const float* hidden = (const float*)d_in[0];   // (1, 32, 1024) fp32
    const float* enc    = (const float*)d_in[1];   // (32, 1024, 1024) fp32
    const float* W      = (const float*)d_in[2];   // (1024, 2048) fp32
    const float* bias   = (const float*)d_in[3];   // (1024,) fp32
    const float* v      = (const float*)d_in[4];   // (1024,) fp32
    float* out = (float*)d_out;                    // (32, 1, 1024) fp32

    char* ws = (char*)d_ws;
    float*    q     = (float*)ws;                            // 128 KB
    float*    energ = (float*)(ws + 131072);                 // 2 MB (16 partials x M_TOT)
    _Float16* We16  = (_Float16*)(ws + 131072 + 2097152);    // 2 MB
    _Float16* enc16 = (_Float16*)(ws + 131072 + 2097152 + 2097152);  // 64 MB
    const size_t need_fast = 131072 + 2097152 + 2097152 + (size_t)M_TOT * HDIM * 2;  // ~68 MB

    if (ws_size >= need_fast) {
        prep_k<<<dim3(18432), 256, 0, stream>>>(W, hidden, bias, enc, We16, q, enc16);
        attn_gemm_db_k<<<dim3(2048), 256, 0, stream>>>(enc16, We16, q, v, energ);
    } else {
        prep_k<<<dim3(2048), 256, 0, stream>>>(W, hidden, bias, enc, We16, q, enc16);
        attn_gemm_k<<<dim3(256, 8), 256, 0, stream>>>(enc, We16, q, v, energ);
    }
    softmax_k<<<dim3(BATCH), 256, 0, stream>>>(energ, out);
}